// Round 10
// baseline (359.619 us; speedup 1.0000x reference)
//
#include <hip/hip_runtime.h>
#include <hip/hip_cooperative_groups.h>
#include <stdint.h>

namespace cg = cooperative_groups;

#define B_ 8
#define S_ 1024
#define H_ 768
#define NH_ 12
#define HD_ 64
#define M_ (B_*S_)   // 8192 tokens

typedef __attribute__((ext_vector_type(8))) short short8;
typedef __attribute__((ext_vector_type(8))) ushort ushort8;
typedef __attribute__((ext_vector_type(4))) float floatx4;

#define MFMA16(a,b,c) __builtin_amdgcn_mfma_f32_16x16x32_bf16((a),(b),(c),0,0,0)

__device__ __forceinline__ ushort f2bf(float x){
    union { float f; unsigned u; } v; v.f = x;
    unsigned r = (v.u + 0x7fffu + ((v.u >> 16) & 1u)) >> 16;
    return (ushort)r;
}

__device__ __forceinline__ void async16(const ushort* g, ushort* l){
    __builtin_amdgcn_global_load_lds(
        (const __attribute__((address_space(1))) unsigned int*)g,
        (__attribute__((address_space(3))) unsigned int*)l, 16, 0, 0);
}

// ---------------- fused f32 -> bf16 cast for all 6 tensors ----------------
// 8 elements/thread: 2x float4 load, one 16 B ushort8 store
__global__ __launch_bounds__(256, 8) void cvt_all(
    const float* __restrict__ hs, const float* __restrict__ ce,
    const float* __restrict__ wq, const float* __restrict__ wk,
    const float* __restrict__ wv, const float* __restrict__ wo,
    ushort* __restrict__ hsb, ushort* __restrict__ ceb,
    ushort* __restrict__ wqb, ushort* __restrict__ wkb,
    ushort* __restrict__ wvb, ushort* __restrict__ wob)
{
    const int NA = M_*H_/8;      // 8-elem chunks per activation tensor
    const int NW = H_*H_/8;      // 8-elem chunks per weight tensor
    int i = blockIdx.x*256 + threadIdx.x;
    if (i >= 2*NA + 4*NW) return;
    const float* s; ushort* d; int off;
    if (i < NA)            { s = hs; d = hsb; off = i; }
    else if (i < 2*NA)     { s = ce; d = ceb; off = i - NA; }
    else {
        int j = i - 2*NA;
        int wsel = j / NW;
        off = j - wsel*NW;
        s = (wsel==0) ? wq : (wsel==1) ? wk : (wsel==2) ? wv : wo;
        d = (wsel==0) ? wqb : (wsel==1) ? wkb : (wsel==2) ? wvb : wob;
    }
    float4 f0 = ((const float4*)s)[2*off];
    float4 f1 = ((const float4*)s)[2*off + 1];
    ushort8 u;
    u[0] = f2bf(f0.x); u[1] = f2bf(f0.y); u[2] = f2bf(f0.z); u[3] = f2bf(f0.w);
    u[4] = f2bf(f1.x); u[5] = f2bf(f1.y); u[6] = f2bf(f1.z); u[7] = f2bf(f1.w);
    ((ushort8*)d)[off] = u;
}

// ---------------- shared GEMM body: C[M,N] = A[M,K] @ B[N,K]^T + bias ------
// BK=64, XOR-swizzled 128B-pitch LDS rows. smem is DECLARED BY THE CALLER
// and passed in (round-8 lesson: per-instantiation __shared__ in a
// dual-MODE kernel doubles the LDS allocation and halves occupancy).
// MODE 0: bf16 out [M,768]; MODE 1 (BN=96): Vt[(b*12+h)*64+d][1024] via
// single-phase LDS-assembled coalesced stores; MODE 2: f32 out + residual.
template<int BN, int MODE>
__device__ __forceinline__ void gemm_body(
    ushort* __restrict__ smem,
    const ushort* __restrict__ A, const ushort* __restrict__ Bw,
    const float* __restrict__ bias, ushort* __restrict__ obf,
    float* __restrict__ of32, const float* __restrict__ resid,
    int bx, int by)
{
    constexpr int NT = BN/32;               // col tiles per wave half
    ushort* lA = smem;                      // [0, 8192)
    ushort* lB = smem + 8192;               // [8192, 8192+BN*64)
    const int K = H_;
    int tid  = threadIdx.x;
    int lane = tid & 63, wave = tid >> 6;
    int m0 = bx * 128, n0 = by * BN;
    int wm = (wave >> 1) * 64, wn = (wave & 1) * (BN/2);
    int fr = lane & 15, quad = lane >> 4, quad4 = quad*4;

    floatx4 acc[4][NT];
    #pragma unroll
    for (int mt=0;mt<4;mt++)
        #pragma unroll
        for (int nt=0;nt<NT;nt++)
            acc[mt][nt] = (floatx4){0.f,0.f,0.f,0.f};

    // staging: chunk n = tid + 256*j; row = n>>3 (row0+32j),
    // logical col chunk c = n&7, swizzled source col = (c ^ (row&7))*8
    int row0 = tid >> 3;
    int csw  = ((tid & 7) ^ (row0 & 7)) * 8;   // same for all j (32j & 7 == 0)
    const ushort* Ap[4]; const ushort* Bp[NT];
    ushort* ldA_[4]; ushort* ldB_[NT];
    #pragma unroll
    for (int j=0;j<4;j++){
        int row = row0 + 32*j;
        Ap[j] = A + (size_t)(m0 + row) * K + csw;
        ldA_[j] = lA + (tid + 256*j)*8;
    }
    #pragma unroll
    for (int j=0;j<NT;j++){
        int row = row0 + 32*j;
        Bp[j] = Bw + (size_t)(n0 + row) * K + csw;
        ldB_[j] = lB + (tid + 256*j)*8;
    }

    for (int k0 = 0; k0 < K; k0 += 64){
        #pragma unroll
        for (int j=0;j<4;j++) async16(Ap[j] + k0, ldA_[j]);
        #pragma unroll
        for (int j=0;j<NT;j++) async16(Bp[j] + k0, ldB_[j]);
        __syncthreads();
        #pragma unroll
        for (int kk=0; kk<2; kk++){
            short8 af[4], bfr[NT];
            #pragma unroll
            for (int t=0;t<4;t++){
                int ra = wm + t*16 + fr;
                af[t]  = *(const short8*)&lA[ra*64 + (((kk*4+quad) ^ (ra&7))<<3)];
            }
            #pragma unroll
            for (int t=0;t<NT;t++){
                int rb = wn + t*16 + fr;
                bfr[t] = *(const short8*)&lB[rb*64 + (((kk*4+quad) ^ (rb&7))<<3)];
            }
            #pragma unroll
            for (int mt=0;mt<4;mt++)
                #pragma unroll
                for (int nt=0;nt<NT;nt++)
                    acc[mt][nt] = MFMA16(af[mt], bfr[nt], acc[mt][nt]);
        }
        __syncthreads();
    }

    float bv_[NT];
    #pragma unroll
    for (int nt=0;nt<NT;nt++) bv_[nt] = bias[n0 + wn + nt*16 + fr];

    if constexpr (MODE == 0){
        #pragma unroll
        for (int mt=0;mt<4;mt++){
            int rb = m0 + wm + mt*16 + quad4;
            #pragma unroll
            for (int nt=0;nt<NT;nt++){
                int col = n0 + wn + nt*16 + fr;
                #pragma unroll
                for (int r=0;r<4;r++)
                    obf[(size_t)(rb + r)*H_ + col] = f2bf(acc[mt][nt][r] + bv_[nt]);
            }
        }
    } else if constexpr (MODE == 1){
        // Vt assembly (BN=96): [96 d][pitch 136 q] in smem,
        // single phase: K-loop's trailing barrier means smem is free now.
        int bb = m0 >> 10, q0 = m0 & 1023;
        #pragma unroll
        for (int mt=0;mt<4;mt++){
            int ql = wm + mt*16 + quad4;
            #pragma unroll
            for (int nt=0;nt<NT;nt++){
                int dl = wn + nt*16 + fr;      // 0..95
                ushort4 u;
                u.x = f2bf(acc[mt][nt][0] + bv_[nt]);
                u.y = f2bf(acc[mt][nt][1] + bv_[nt]);
                u.z = f2bf(acc[mt][nt][2] + bv_[nt]);
                u.w = f2bf(acc[mt][nt][3] + bv_[nt]);
                *(ushort4*)&smem[dl*136 + ql] = u;
            }
        }
        __syncthreads();
        #pragma unroll
        for (int jj=0;jj<6;jj++){
            int mI = tid + 256*jj;             // 0..1535
            int d  = mI >> 4;                  // 0..95
            int qc = (mI & 15) * 8;            // 0..120
            short8 v = *(const short8*)&smem[d*136 + qc];
            int gcol = by*96 + d;
            int h = gcol >> 6, dd = gcol & 63;
            *(short8*)&obf[((size_t)((bb*NH_ + h)*HD_ + dd))*S_ + q0 + qc] = v;
        }
    } else {
        #pragma unroll
        for (int mt=0;mt<4;mt++){
            int rb = m0 + wm + mt*16 + quad4;
            #pragma unroll
            for (int nt=0;nt<NT;nt++){
                int col = n0 + wn + nt*16 + fr;
                #pragma unroll
                for (int r=0;r<4;r++){
                    size_t idx = (size_t)(rb + r)*H_ + col;
                    of32[idx] = acc[mt][nt][r] + bv_[nt] + resid[idx];
                }
            }
        }
    }
}

// fused Q/K/V projection: grid (64, 8, 3), BN=96 (1536 blocks = two full
// rounds at 3 blocks/CU). Single 28672 B __shared__ allocation.
__global__ __launch_bounds__(256, 3) void gemm_qkv(
    const ushort* __restrict__ hsb, const ushort* __restrict__ ceb,
    const ushort* __restrict__ wqb, const ushort* __restrict__ wkb,
    const ushort* __restrict__ wvb,
    const float* __restrict__ bq, const float* __restrict__ bk,
    const float* __restrict__ bv,
    ushort* __restrict__ Qb, ushort* __restrict__ Kb, ushort* __restrict__ Vtb)
{
    __shared__ ushort smem[8192 + 96*64];   // 28672 B, single allocation
    int z = blockIdx.z;
    const ushort* A  = (z==0) ? hsb : ceb;
    const ushort* Bw = (z==0) ? wqb : (z==1) ? wkb : wvb;
    const float* bias = (z==0) ? bq : (z==1) ? bk : bv;
    if (z == 2)
        gemm_body<96,1>(smem, A, Bw, bias, Vtb, nullptr, nullptr,
                        blockIdx.x, blockIdx.y);
    else
        gemm_body<96,0>(smem, A, Bw, bias, (z==0)?Qb:Kb, nullptr, nullptr,
                        blockIdx.x, blockIdx.y);
}

// O-projection + residual + LayerNorm, cooperatively merged.
// Phase 1: gemm_body<96,2> writes proj = ctx@Wo^T + bo + hs (f32).
// grid.sync(). Phase 2: LN over 16 rows/block, ONE WAVE PER ROW
// (64 lanes x 3 float4 = 768 floats; pure shfl reduce, no LDS).
// grid (64,8) = 512 blocks at 3 blocks/CU (cap 768) -> cooperative-legal.
// Mechanisms: one less launch+gap; proj re-read is L2-warm.
__global__ __launch_bounds__(256, 3) void gemm_o_ln(
    const ushort* __restrict__ ctxb, const ushort* __restrict__ wob,
    const float* __restrict__ bo, const float* __restrict__ hs,
    float* __restrict__ proj,
    const float* __restrict__ g, const float* __restrict__ be,
    float* __restrict__ out)
{
    __shared__ ushort smem[8192 + 96*64];   // 28672 B
    gemm_body<96,2>(smem, ctxb, wob, bo, nullptr, proj, hs,
                    blockIdx.x, blockIdx.y);

    __threadfence();                 // device-scope release of proj stores
    cg::this_grid().sync();          // all proj writes done grid-wide

    int tid  = threadIdx.x;
    int lane = tid & 63, w4 = tid >> 6;
    int lin  = blockIdx.y * gridDim.x + blockIdx.x;   // 0..511
    #pragma unroll
    for (int it = 0; it < 4; ++it){
        int row = lin*16 + it*4 + w4;                 // 512*16 = 8192 rows
        const float* pr = proj + (size_t)row * H_;
        float4 v0 = ((const float4*)pr)[lane];
        float4 v1 = ((const float4*)pr)[lane + 64];
        float4 v2 = ((const float4*)pr)[lane + 128];
        float s  = (v0.x+v0.y+v0.z+v0.w) + (v1.x+v1.y+v1.z+v1.w)
                 + (v2.x+v2.y+v2.z+v2.w);
        float s2 = (v0.x*v0.x+v0.y*v0.y+v0.z*v0.z+v0.w*v0.w)
                 + (v1.x*v1.x+v1.y*v1.y+v1.z*v1.z+v1.w*v1.w)
                 + (v2.x*v2.x+v2.y*v2.y+v2.z*v2.z+v2.w*v2.w);
        #pragma unroll
        for (int off=1; off<64; off<<=1){
            s  += __shfl_xor(s,  off);
            s2 += __shfl_xor(s2, off);
        }
        float mu  = s * (1.f/H_);
        float var = s2*(1.f/H_) - mu*mu;
        float rinv = rsqrtf(var + 1e-5f);
        float4 g0 = ((const float4*)g)[lane];
        float4 g1 = ((const float4*)g)[lane + 64];
        float4 g2 = ((const float4*)g)[lane + 128];
        float4 b0 = ((const float4*)be)[lane];
        float4 b1 = ((const float4*)be)[lane + 64];
        float4 b2 = ((const float4*)be)[lane + 128];
        float* po = out + (size_t)row * H_;
        float4 o0, o1, o2;
        o0.x=(v0.x-mu)*rinv*g0.x+b0.x; o0.y=(v0.y-mu)*rinv*g0.y+b0.y;
        o0.z=(v0.z-mu)*rinv*g0.z+b0.z; o0.w=(v0.w-mu)*rinv*g0.w+b0.w;
        o1.x=(v1.x-mu)*rinv*g1.x+b1.x; o1.y=(v1.y-mu)*rinv*g1.y+b1.y;
        o1.z=(v1.z-mu)*rinv*g1.z+b1.z; o1.w=(v1.w-mu)*rinv*g1.w+b1.w;
        o2.x=(v2.x-mu)*rinv*g2.x+b2.x; o2.y=(v2.y-mu)*rinv*g2.y+b2.y;
        o2.z=(v2.z-mu)*rinv*g2.z+b2.z; o2.w=(v2.w-mu)*rinv*g2.w+b2.w;
        ((float4*)po)[lane]       = o0;
        ((float4*)po)[lane + 64]  = o1;
        ((float4*)po)[lane + 128] = o2;
    }
}

// ---------------- flash attention (S^T formulation) ----------------
// grid: B*NH*8 blocks; block = (b, h, 128 q-rows); 4 waves x 32 q-rows
// FROZEN = round-5 v6 verbatim (44.0us, four-times-measured): round-0
// body + s_setprio around MFMA clusters. Do not touch loop structure.
__global__ __launch_bounds__(256, 3) void attn(
    const ushort* __restrict__ Q, const ushort* __restrict__ Kc,
    const ushort* __restrict__ Vt, const float* __restrict__ mask,
    ushort* __restrict__ ctx)
{
    __shared__ ushort lK[64*64];
    __shared__ ushort lV[64*64];
    __shared__ ushort lP[4][32*72];
    __shared__ float  lmask[S_];
    __shared__ float  linv[4][32];

    const float SC = 0.125f * 1.44269504f;

    int bid = blockIdx.x;
    int qt = bid & 7;
    int h  = (bid >> 3) % NH_;
    int b  = bid / (8*NH_);

    int tid  = threadIdx.x;
    int lane = tid & 63, w = tid >> 6;
    int fr = lane & 15, quad = lane >> 4;
    int quad4 = quad*4, sw = fr & 7;

    for (int i = tid; i < S_; i += 256)
        lmask[i] = (1.0f - mask[b*S_ + i]) * -14426.95f;

    short8 qf[2][2];
    #pragma unroll
    for (int nq=0;nq<2;nq++){
        const ushort* Qp = Q + (size_t)(b*S_ + qt*128 + w*32 + nq*16 + fr)*H_ + h*HD_ + quad*8;
        qf[nq][0] = *(const short8*)(Qp);
        qf[nq][1] = *(const short8*)(Qp + 32);
    }

    floatx4 O[2][4];
    #pragma unroll
    for (int mt=0;mt<2;mt++)
        #pragma unroll
        for (int nt=0;nt<4;nt++)
            O[mt][nt] = (floatx4){0.f,0.f,0.f,0.f};
    float rs0 = 0.f, rs1 = 0.f;

    int n0 = tid,       r0 = n0 >> 3, c0 = (n0 & 7) ^ (r0 & 7);
    int n1 = 256 + tid, r1 = n1 >> 3, c1 = (n1 & 7) ^ (r1 & 7);
    const ushort* pK0 = Kc + (size_t)(b*S_ + r0)*H_ + h*HD_ + c0*8;
    const ushort* pK1 = Kc + (size_t)(b*S_ + r1)*H_ + h*HD_ + c1*8;
    const ushort* pV0 = Vt + ((size_t)(b*NH_ + h)*HD_ + r0)*S_ + c0*8;
    const ushort* pV1 = Vt + ((size_t)(b*NH_ + h)*HD_ + r1)*S_ + c1*8;
    ushort* dK0 = &lK[n0*8]; ushort* dK1 = &lK[n1*8];
    ushort* dV0 = &lV[n0*8]; ushort* dV1 = &lV[n1*8];

    ushort* lPw = &lP[w][0];

    for (int kt = 0; kt < 16; kt++){
        __syncthreads();
        async16(pK0, dK0); async16(pK1, dK1);
        async16(pV0, dV0); async16(pV1, dV1);
        pK0 += (size_t)64*H_; pK1 += (size_t)64*H_;
        pV0 += 64; pV1 += 64;
        __syncthreads();

        float4 mk4[4];
        #pragma unroll
        for (int mk=0;mk<4;mk++)
            mk4[mk] = *(const float4*)&lmask[kt*64 + mk*16 + quad4];

        short8 kf[4][2];
        #pragma unroll
        for (int mk=0;mk<4;mk++){
            int row = mk*16 + fr;
            kf[mk][0] = *(const short8*)&lK[row*64 + ((quad     ^ sw)<<3)];
            kf[mk][1] = *(const short8*)&lK[row*64 + (((4+quad) ^ sw)<<3)];
        }
        __builtin_amdgcn_s_setprio(1);
        floatx4 st[2][4];
        #pragma unroll
        for (int nq=0;nq<2;nq++)
            #pragma unroll
            for (int mk=0;mk<4;mk++){
                floatx4 a = (floatx4){0.f,0.f,0.f,0.f};
                a = MFMA16(kf[mk][0], qf[nq][0], a);
                a = MFMA16(kf[mk][1], qf[nq][1], a);
                st[nq][mk] = a;
            }
        __builtin_amdgcn_s_setprio(0);

        #pragma unroll
        for (int nq=0;nq<2;nq++){
            #pragma unroll
            for (int mk=0;mk<4;mk++){
                floatx4 s = st[nq][mk];
                #pragma unroll
                for (int r=0;r<4;r++)
                    s[r] = __builtin_amdgcn_exp2f(s[r]*SC + mk4[mk][r]);
                if (nq == 0) rs0 += (s[0]+s[1]) + (s[2]+s[3]);
                else         rs1 += (s[0]+s[1]) + (s[2]+s[3]);
                unsigned lo = __builtin_amdgcn_perm(__float_as_uint(s[1]), __float_as_uint(s[0]), 0x07060302u);
                unsigned hi = __builtin_amdgcn_perm(__float_as_uint(s[3]), __float_as_uint(s[2]), 0x07060302u);
                uint2 pk; pk.x = lo; pk.y = hi;
                *(uint2*)&lPw[(nq*16 + fr)*72 + mk*16 + quad4] = pk;
            }
        }

        short8 vf[4][2];
        #pragma unroll
        for (int nt=0;nt<4;nt++){
            int row = nt*16 + fr;
            vf[nt][0] = *(const short8*)&lV[row*64 + ((quad     ^ sw)<<3)];
            vf[nt][1] = *(const short8*)&lV[row*64 + (((4+quad) ^ sw)<<3)];
        }
        short8 pf[2][2];
        #pragma unroll
        for (int mt=0;mt<2;mt++){
            pf[mt][0] = *(const short8*)&lPw[(mt*16+fr)*72 + quad*8];
            pf[mt][1] = *(const short8*)&lPw[(mt*16+fr)*72 + 32 + quad*8];
        }
        __builtin_amdgcn_s_setprio(1);
        #pragma unroll
        for (int mt=0;mt<2;mt++)
            #pragma unroll
            for (int nt=0;nt<4;nt++){
                O[mt][nt] = MFMA16(pf[mt][0], vf[nt][0], O[mt][nt]);
                O[mt][nt] = MFMA16(pf[mt][1], vf[nt][1], O[mt][nt]);
            }
        __builtin_amdgcn_s_setprio(0);
    }

    rs0 += __shfl_xor(rs0, 16); rs0 += __shfl_xor(rs0, 32);
    rs1 += __shfl_xor(rs1, 16); rs1 += __shfl_xor(rs1, 32);
    if (lane < 16){
        linv[w][fr]      = 1.0f / rs0;
        linv[w][16 + fr] = 1.0f / rs1;
    }
    int tokbase = b*S_ + qt*128 + w*32;
    #pragma unroll
    for (int mt=0;mt<2;mt++){
        float4 iv = *(const float4*)&linv[w][mt*16 + quad4];
        #pragma unroll
        for (int nt=0;nt<4;nt++)
            #pragma unroll
            for (int r=0;r<4;r++){
                int tok = tokbase + mt*16 + quad4 + r;
                ctx[(size_t)tok*H_ + h*HD_ + nt*16 + fr] = f2bf(O[mt][nt][r] * (&iv.x)[r]);
            }
    }
}

extern "C" void kernel_launch(void* const* d_in, const int* in_sizes, int n_in,
                              void* d_out, int out_size, void* d_ws, size_t ws_size,
                              hipStream_t stream)
{
    (void)in_sizes; (void)n_in; (void)out_size; (void)ws_size;
    const float* hs   = (const float*)d_in[0];
    const float* ce   = (const float*)d_in[1];
    const float* mask = (const float*)d_in[2];
    const float* Wq   = (const float*)d_in[3];
    const float* bq   = (const float*)d_in[4];
    const float* Wk   = (const float*)d_in[5];
    const float* bk   = (const float*)d_in[6];
    const float* Wv   = (const float*)d_in[7];
    const float* bv   = (const float*)d_in[8];
    const float* Wo   = (const float*)d_in[9];
    const float* bo   = (const float*)d_in[10];
    const float* lg   = (const float*)d_in[11];
    const float* lb   = (const float*)d_in[12];
    float* out = (float*)d_out;

    char* ws = (char*)d_ws;
    const size_t SZ_ACT = (size_t)M_*H_*2;
    const size_t SZ_W   = (size_t)H_*H_*2;
    ushort* hsb  = (ushort*)(ws);
    ushort* ceb  = (ushort*)(ws + SZ_ACT);
    ushort* wqb  = (ushort*)(ws + 2*SZ_ACT);
    ushort* wkb  = (ushort*)(ws + 2*SZ_ACT + 1*SZ_W);
    ushort* wvb  = (ushort*)(ws + 2*SZ_ACT + 2*SZ_W);
    ushort* wob  = (ushort*)(ws + 2*SZ_ACT + 3*SZ_W);
    ushort* Qb   = (ushort*)(ws + 2*SZ_ACT + 4*SZ_W);
    ushort* Kb   = (ushort*)(ws + 3*SZ_ACT + 4*SZ_W);
    ushort* Vtb  = (ushort*)(ws + 4*SZ_ACT + 4*SZ_W);
    ushort* ctxb = (ushort*)(ws + 5*SZ_ACT + 4*SZ_W);
    float*  proj = (float*)(ws);  // aliases hsb+ceb (dead after QKV GEMMs)

    int ncvt = 2*(M_*H_/8) + 4*(H_*H_/8);
    cvt_all<<<dim3((ncvt+255)/256), dim3(256), 0, stream>>>(
        hs, ce, Wq, Wk, Wv, Wo, hsb, ceb, wqb, wkb, wvb, wob);

    gemm_qkv<<<dim3(M_/128, H_/96, 3), dim3(256), 0, stream>>>(
        hsb, ceb, wqb, wkb, wvb, bq, bk, bv, Qb, Kb, Vtb);

    attn<<<dim3(B_*NH_*8), dim3(256), 0, stream>>>(Qb, Kb, Vtb, mask, ctxb);

    // cooperative launch: phase-1 GEMM+residual, grid.sync, phase-2 LN
    void* args[] = { (void*)&ctxb, (void*)&wob, (void*)&bo, (void*)&hs,
                     (void*)&proj, (void*)&lg, (void*)&lb, (void*)&out };
    hipLaunchCooperativeKernel((const void*)gemm_o_ln,
                               dim3(M_/128, H_/96), dim3(256),
                               args, 0, stream);
}

// Round 11
// 221.853 us; speedup vs baseline: 1.6210x; 1.6210x over previous
//
#include <hip/hip_runtime.h>
#include <stdint.h>

#define B_ 8
#define S_ 1024
#define H_ 768
#define NH_ 12
#define HD_ 64
#define M_ (B_*S_)   // 8192 tokens

typedef __attribute__((ext_vector_type(8))) short short8;
typedef __attribute__((ext_vector_type(8))) ushort ushort8;
typedef __attribute__((ext_vector_type(4))) float floatx4;

#define MFMA16(a,b,c) __builtin_amdgcn_mfma_f32_16x16x32_bf16((a),(b),(c),0,0,0)

__device__ __forceinline__ ushort f2bf(float x){
    union { float f; unsigned u; } v; v.f = x;
    unsigned r = (v.u + 0x7fffu + ((v.u >> 16) & 1u)) >> 16;
    return (ushort)r;
}

__device__ __forceinline__ void async16(const ushort* g, ushort* l){
    __builtin_amdgcn_global_load_lds(
        (const __attribute__((address_space(1))) unsigned int*)g,
        (__attribute__((address_space(3))) unsigned int*)l, 16, 0, 0);
}

// ---------------- fused f32 -> bf16 cast for all 6 tensors ----------------
// 8 elements/thread: 2x float4 load, one 16 B ushort8 store
__global__ __launch_bounds__(256, 8) void cvt_all(
    const float* __restrict__ hs, const float* __restrict__ ce,
    const float* __restrict__ wq, const float* __restrict__ wk,
    const float* __restrict__ wv, const float* __restrict__ wo,
    ushort* __restrict__ hsb, ushort* __restrict__ ceb,
    ushort* __restrict__ wqb, ushort* __restrict__ wkb,
    ushort* __restrict__ wvb, ushort* __restrict__ wob)
{
    const int NA = M_*H_/8;
    const int NW = H_*H_/8;
    int i = blockIdx.x*256 + threadIdx.x;
    if (i >= 2*NA + 4*NW) return;
    const float* s; ushort* d; int off;
    if (i < NA)            { s = hs; d = hsb; off = i; }
    else if (i < 2*NA)     { s = ce; d = ceb; off = i - NA; }
    else {
        int j = i - 2*NA;
        int wsel = j / NW;
        off = j - wsel*NW;
        s = (wsel==0) ? wq : (wsel==1) ? wk : (wsel==2) ? wv : wo;
        d = (wsel==0) ? wqb : (wsel==1) ? wkb : (wsel==2) ? wvb : wob;
    }
    float4 f0 = ((const float4*)s)[2*off];
    float4 f1 = ((const float4*)s)[2*off + 1];
    ushort8 u;
    u[0] = f2bf(f0.x); u[1] = f2bf(f0.y); u[2] = f2bf(f0.z); u[3] = f2bf(f0.w);
    u[4] = f2bf(f1.x); u[5] = f2bf(f1.y); u[6] = f2bf(f1.z); u[7] = f2bf(f1.w);
    ((ushort8*)d)[off] = u;
}

// ---------------- shared GEMM body: C[M,N] = A[M,K] @ B[N,K]^T + bias ------
// BK=64, XOR-swizzled 128B-pitch LDS rows. smem DECLARED BY CALLER (round-8
// lesson: per-instantiation __shared__ doubles LDS, halves occupancy).
// MODE 0: bf16 out; MODE 1 (BN=96): Vt via LDS-assembled coalesced stores;
// MODE 2: f32 out + residual.
template<int BN, int MODE>
__device__ __forceinline__ void gemm_body(
    ushort* __restrict__ smem,
    const ushort* __restrict__ A, const ushort* __restrict__ Bw,
    const float* __restrict__ bias, ushort* __restrict__ obf,
    float* __restrict__ of32, const float* __restrict__ resid,
    int bx, int by)
{
    constexpr int NT = BN/32;
    ushort* lA = smem;                      // [0, 8192)
    ushort* lB = smem + 8192;               // [8192, 8192+BN*64)
    const int K = H_;
    int tid  = threadIdx.x;
    int lane = tid & 63, wave = tid >> 6;
    int m0 = bx * 128, n0 = by * BN;
    int wm = (wave >> 1) * 64, wn = (wave & 1) * (BN/2);
    int fr = lane & 15, quad = lane >> 4, quad4 = quad*4;

    floatx4 acc[4][NT];
    #pragma unroll
    for (int mt=0;mt<4;mt++)
        #pragma unroll
        for (int nt=0;nt<NT;nt++)
            acc[mt][nt] = (floatx4){0.f,0.f,0.f,0.f};

    int row0 = tid >> 3;
    int csw  = ((tid & 7) ^ (row0 & 7)) * 8;
    const ushort* Ap[4]; const ushort* Bp[NT];
    ushort* ldA_[4]; ushort* ldB_[NT];
    #pragma unroll
    for (int j=0;j<4;j++){
        int row = row0 + 32*j;
        Ap[j] = A + (size_t)(m0 + row) * K + csw;
        ldA_[j] = lA + (tid + 256*j)*8;
    }
    #pragma unroll
    for (int j=0;j<NT;j++){
        int row = row0 + 32*j;
        Bp[j] = Bw + (size_t)(n0 + row) * K + csw;
        ldB_[j] = lB + (tid + 256*j)*8;
    }

    for (int k0 = 0; k0 < K; k0 += 64){
        #pragma unroll
        for (int j=0;j<4;j++) async16(Ap[j] + k0, ldA_[j]);
        #pragma unroll
        for (int j=0;j<NT;j++) async16(Bp[j] + k0, ldB_[j]);
        __syncthreads();
        #pragma unroll
        for (int kk=0; kk<2; kk++){
            short8 af[4], bfr[NT];
            #pragma unroll
            for (int t=0;t<4;t++){
                int ra = wm + t*16 + fr;
                af[t]  = *(const short8*)&lA[ra*64 + (((kk*4+quad) ^ (ra&7))<<3)];
            }
            #pragma unroll
            for (int t=0;t<NT;t++){
                int rb = wn + t*16 + fr;
                bfr[t] = *(const short8*)&lB[rb*64 + (((kk*4+quad) ^ (rb&7))<<3)];
            }
            #pragma unroll
            for (int mt=0;mt<4;mt++)
                #pragma unroll
                for (int nt=0;nt<NT;nt++)
                    acc[mt][nt] = MFMA16(af[mt], bfr[nt], acc[mt][nt]);
        }
        __syncthreads();
    }

    float bv_[NT];
    #pragma unroll
    for (int nt=0;nt<NT;nt++) bv_[nt] = bias[n0 + wn + nt*16 + fr];

    if constexpr (MODE == 0){
        #pragma unroll
        for (int mt=0;mt<4;mt++){
            int rb = m0 + wm + mt*16 + quad4;
            #pragma unroll
            for (int nt=0;nt<NT;nt++){
                int col = n0 + wn + nt*16 + fr;
                #pragma unroll
                for (int r=0;r<4;r++)
                    obf[(size_t)(rb + r)*H_ + col] = f2bf(acc[mt][nt][r] + bv_[nt]);
            }
        }
    } else if constexpr (MODE == 1){
        int bb = m0 >> 10, q0 = m0 & 1023;
        #pragma unroll
        for (int mt=0;mt<4;mt++){
            int ql = wm + mt*16 + quad4;
            #pragma unroll
            for (int nt=0;nt<NT;nt++){
                int dl = wn + nt*16 + fr;      // 0..95
                ushort4 u;
                u.x = f2bf(acc[mt][nt][0] + bv_[nt]);
                u.y = f2bf(acc[mt][nt][1] + bv_[nt]);
                u.z = f2bf(acc[mt][nt][2] + bv_[nt]);
                u.w = f2bf(acc[mt][nt][3] + bv_[nt]);
                *(ushort4*)&smem[dl*136 + ql] = u;
            }
        }
        __syncthreads();
        #pragma unroll
        for (int jj=0;jj<6;jj++){
            int mI = tid + 256*jj;             // 0..1535
            int d  = mI >> 4;                  // 0..95
            int qc = (mI & 15) * 8;            // 0..120
            short8 v = *(const short8*)&smem[d*136 + qc];
            int gcol = by*96 + d;
            int h = gcol >> 6, dd = gcol & 63;
            *(short8*)&obf[((size_t)((bb*NH_ + h)*HD_ + dd))*S_ + q0 + qc] = v;
        }
    } else {
        #pragma unroll
        for (int mt=0;mt<4;mt++){
            int rb = m0 + wm + mt*16 + quad4;
            #pragma unroll
            for (int nt=0;nt<NT;nt++){
                int col = n0 + wn + nt*16 + fr;
                #pragma unroll
                for (int r=0;r<4;r++){
                    size_t idx = (size_t)(rb + r)*H_ + col;
                    of32[idx] = acc[mt][nt][r] + bv_[nt] + resid[idx];
                }
            }
        }
    }
}

// -------- merged K+V body: both 96-col panels share ONE staged A tile -----
// 48 MFMA per barrier pair (vs 24 in two separate blocks) -> per-MFMA
// barrier/drain stalls halved on 2/3 of QKV work. acc 96 floats + frags
// ~160 VGPR < 170 cap @ 3 blocks/CU. LDS 40960 B -> 3 blocks/CU holds.
__device__ __forceinline__ void gemm_kv_body(
    ushort* __restrict__ smem,
    const ushort* __restrict__ A,
    const ushort* __restrict__ Bk, const ushort* __restrict__ Bv,
    const float* __restrict__ biask, const float* __restrict__ biasv,
    ushort* __restrict__ Kb, ushort* __restrict__ Vtb,
    int bx, int by)
{
    ushort* lA  = smem;             // 8192 ushorts
    ushort* lBK = smem + 8192;      // 6144
    ushort* lBV = smem + 14336;     // 6144
    const int K = H_;
    int tid  = threadIdx.x;
    int lane = tid & 63, wave = tid >> 6;
    int m0 = bx * 128, n0 = by * 96;
    int wm = (wave >> 1) * 64, wn = (wave & 1) * 48;
    int fr = lane & 15, quad = lane >> 4, quad4 = quad*4;

    floatx4 aK[4][3], aV[4][3];
    #pragma unroll
    for (int mt=0;mt<4;mt++)
        #pragma unroll
        for (int nt=0;nt<3;nt++){
            aK[mt][nt] = (floatx4){0.f,0.f,0.f,0.f};
            aV[mt][nt] = (floatx4){0.f,0.f,0.f,0.f};
        }

    int row0 = tid >> 3;
    int csw  = ((tid & 7) ^ (row0 & 7)) * 8;
    const ushort* Ap[4]; const ushort* Kp[3]; const ushort* Vp[3];
    ushort* ldA_[4]; ushort* ldK_[3]; ushort* ldV_[3];
    #pragma unroll
    for (int j=0;j<4;j++){
        int row = row0 + 32*j;
        Ap[j] = A + (size_t)(m0 + row) * K + csw;
        ldA_[j] = lA + (tid + 256*j)*8;
    }
    #pragma unroll
    for (int j=0;j<3;j++){
        int row = row0 + 32*j;
        Kp[j] = Bk + (size_t)(n0 + row) * K + csw;
        Vp[j] = Bv + (size_t)(n0 + row) * K + csw;
        ldK_[j] = lBK + (tid + 256*j)*8;
        ldV_[j] = lBV + (tid + 256*j)*8;
    }

    for (int k0 = 0; k0 < K; k0 += 64){
        #pragma unroll
        for (int j=0;j<4;j++) async16(Ap[j] + k0, ldA_[j]);
        #pragma unroll
        for (int j=0;j<3;j++) async16(Kp[j] + k0, ldK_[j]);
        #pragma unroll
        for (int j=0;j<3;j++) async16(Vp[j] + k0, ldV_[j]);
        __syncthreads();
        #pragma unroll
        for (int kk=0; kk<2; kk++){
            short8 af[4], bk_[3], bv2_[3];
            #pragma unroll
            for (int t=0;t<4;t++){
                int ra = wm + t*16 + fr;
                af[t] = *(const short8*)&lA[ra*64 + (((kk*4+quad) ^ (ra&7))<<3)];
            }
            #pragma unroll
            for (int t=0;t<3;t++){
                int rb = wn + t*16 + fr;
                int off = (((kk*4+quad) ^ (rb&7))<<3);
                bk_[t]  = *(const short8*)&lBK[rb*64 + off];
                bv2_[t] = *(const short8*)&lBV[rb*64 + off];
            }
            #pragma unroll
            for (int mt=0;mt<4;mt++)
                #pragma unroll
                for (int nt=0;nt<3;nt++){
                    aK[mt][nt] = MFMA16(af[mt], bk_[nt],  aK[mt][nt]);
                    aV[mt][nt] = MFMA16(af[mt], bv2_[nt], aV[mt][nt]);
                }
        }
        __syncthreads();
    }

    float bk4[3], bv4[3];
    #pragma unroll
    for (int nt=0;nt<3;nt++){
        bk4[nt] = biask[n0 + wn + nt*16 + fr];
        bv4[nt] = biasv[n0 + wn + nt*16 + fr];
    }

    // K epilogue (MODE0 pattern)
    #pragma unroll
    for (int mt=0;mt<4;mt++){
        int rb = m0 + wm + mt*16 + quad4;
        #pragma unroll
        for (int nt=0;nt<3;nt++){
            int col = n0 + wn + nt*16 + fr;
            #pragma unroll
            for (int r=0;r<4;r++)
                Kb[(size_t)(rb + r)*H_ + col] = f2bf(aK[mt][nt][r] + bk4[nt]);
        }
    }

    // V epilogue (MODE1 pattern, BN=96 single phase; smem free after K-loop)
    int bb = m0 >> 10, q0 = m0 & 1023;
    #pragma unroll
    for (int mt=0;mt<4;mt++){
        int ql = wm + mt*16 + quad4;
        #pragma unroll
        for (int nt=0;nt<3;nt++){
            int dl = wn + nt*16 + fr;          // 0..95
            ushort4 u;
            u.x = f2bf(aV[mt][nt][0] + bv4[nt]);
            u.y = f2bf(aV[mt][nt][1] + bv4[nt]);
            u.z = f2bf(aV[mt][nt][2] + bv4[nt]);
            u.w = f2bf(aV[mt][nt][3] + bv4[nt]);
            *(ushort4*)&smem[dl*136 + ql] = u;
        }
    }
    __syncthreads();
    #pragma unroll
    for (int jj=0;jj<6;jj++){
        int mI = tid + 256*jj;                 // 0..1535
        int d  = mI >> 4;                      // 0..95
        int qc = (mI & 15) * 8;
        short8 v = *(const short8*)&smem[d*136 + qc];
        int gcol = by*96 + d;
        int h = gcol >> 6, dd = gcol & 63;
        *(short8*)&Vtb[((size_t)((bb*NH_ + h)*HD_ + dd))*S_ + q0 + qc] = v;
    }
}

// fused Q + merged-KV projection: grid (64, 8, 2).
// z=0: Q (BN=96, A=hs). z=1: K+V merged (shared A=ce stage, 2x acc).
__global__ __launch_bounds__(256, 3) void gemm_qkv(
    const ushort* __restrict__ hsb, const ushort* __restrict__ ceb,
    const ushort* __restrict__ wqb, const ushort* __restrict__ wkb,
    const ushort* __restrict__ wvb,
    const float* __restrict__ bq, const float* __restrict__ bk,
    const float* __restrict__ bv,
    ushort* __restrict__ Qb, ushort* __restrict__ Kb, ushort* __restrict__ Vtb)
{
    __shared__ ushort smem[20480];   // 40960 B single allocation (3 blocks/CU)
    if (blockIdx.z == 0)
        gemm_body<96,0>(smem, hsb, wqb, bq, Qb, nullptr, nullptr,
                        blockIdx.x, blockIdx.y);
    else
        gemm_kv_body(smem, ceb, wkb, wvb, bk, bv, Kb, Vtb,
                     blockIdx.x, blockIdx.y);
}

// O-projection (f32 out, + residual hs fused): grid (64, 8), BN=96
__global__ __launch_bounds__(256, 3) void gemm_o(
    const ushort* __restrict__ ctxb, const ushort* __restrict__ wob,
    const float* __restrict__ bo, const float* __restrict__ hs,
    float* __restrict__ proj)
{
    __shared__ ushort smem[8192 + 96*64];   // 28672 B
    gemm_body<96,2>(smem, ctxb, wob, bo, nullptr, proj, hs,
                    blockIdx.x, blockIdx.y);
}

// ---------------- flash attention (S^T formulation) ----------------
// FROZEN = round-5 v6 verbatim (44.0us, four-times-measured): round-0
// body + s_setprio around MFMA clusters. Do not touch loop structure.
__global__ __launch_bounds__(256, 3) void attn(
    const ushort* __restrict__ Q, const ushort* __restrict__ Kc,
    const ushort* __restrict__ Vt, const float* __restrict__ mask,
    ushort* __restrict__ ctx)
{
    __shared__ ushort lK[64*64];
    __shared__ ushort lV[64*64];
    __shared__ ushort lP[4][32*72];
    __shared__ float  lmask[S_];
    __shared__ float  linv[4][32];

    const float SC = 0.125f * 1.44269504f;

    int bid = blockIdx.x;
    int qt = bid & 7;
    int h  = (bid >> 3) % NH_;
    int b  = bid / (8*NH_);

    int tid  = threadIdx.x;
    int lane = tid & 63, w = tid >> 6;
    int fr = lane & 15, quad = lane >> 4;
    int quad4 = quad*4, sw = fr & 7;

    for (int i = tid; i < S_; i += 256)
        lmask[i] = (1.0f - mask[b*S_ + i]) * -14426.95f;

    short8 qf[2][2];
    #pragma unroll
    for (int nq=0;nq<2;nq++){
        const ushort* Qp = Q + (size_t)(b*S_ + qt*128 + w*32 + nq*16 + fr)*H_ + h*HD_ + quad*8;
        qf[nq][0] = *(const short8*)(Qp);
        qf[nq][1] = *(const short8*)(Qp + 32);
    }

    floatx4 O[2][4];
    #pragma unroll
    for (int mt=0;mt<2;mt++)
        #pragma unroll
        for (int nt=0;nt<4;nt++)
            O[mt][nt] = (floatx4){0.f,0.f,0.f,0.f};
    float rs0 = 0.f, rs1 = 0.f;

    int n0 = tid,       r0 = n0 >> 3, c0 = (n0 & 7) ^ (r0 & 7);
    int n1 = 256 + tid, r1 = n1 >> 3, c1 = (n1 & 7) ^ (r1 & 7);
    const ushort* pK0 = Kc + (size_t)(b*S_ + r0)*H_ + h*HD_ + c0*8;
    const ushort* pK1 = Kc + (size_t)(b*S_ + r1)*H_ + h*HD_ + c1*8;
    const ushort* pV0 = Vt + ((size_t)(b*NH_ + h)*HD_ + r0)*S_ + c0*8;
    const ushort* pV1 = Vt + ((size_t)(b*NH_ + h)*HD_ + r1)*S_ + c1*8;
    ushort* dK0 = &lK[n0*8]; ushort* dK1 = &lK[n1*8];
    ushort* dV0 = &lV[n0*8]; ushort* dV1 = &lV[n1*8];

    ushort* lPw = &lP[w][0];

    for (int kt = 0; kt < 16; kt++){
        __syncthreads();
        async16(pK0, dK0); async16(pK1, dK1);
        async16(pV0, dV0); async16(pV1, dV1);
        pK0 += (size_t)64*H_; pK1 += (size_t)64*H_;
        pV0 += 64; pV1 += 64;
        __syncthreads();

        float4 mk4[4];
        #pragma unroll
        for (int mk=0;mk<4;mk++)
            mk4[mk] = *(const float4*)&lmask[kt*64 + mk*16 + quad4];

        short8 kf[4][2];
        #pragma unroll
        for (int mk=0;mk<4;mk++){
            int row = mk*16 + fr;
            kf[mk][0] = *(const short8*)&lK[row*64 + ((quad     ^ sw)<<3)];
            kf[mk][1] = *(const short8*)&lK[row*64 + (((4+quad) ^ sw)<<3)];
        }
        __builtin_amdgcn_s_setprio(1);
        floatx4 st[2][4];
        #pragma unroll
        for (int nq=0;nq<2;nq++)
            #pragma unroll
            for (int mk=0;mk<4;mk++){
                floatx4 a = (floatx4){0.f,0.f,0.f,0.f};
                a = MFMA16(kf[mk][0], qf[nq][0], a);
                a = MFMA16(kf[mk][1], qf[nq][1], a);
                st[nq][mk] = a;
            }
        __builtin_amdgcn_s_setprio(0);

        #pragma unroll
        for (int nq=0;nq<2;nq++){
            #pragma unroll
            for (int mk=0;mk<4;mk++){
                floatx4 s = st[nq][mk];
                #pragma unroll
                for (int r=0;r<4;r++)
                    s[r] = __builtin_amdgcn_exp2f(s[r]*SC + mk4[mk][r]);
                if (nq == 0) rs0 += (s[0]+s[1]) + (s[2]+s[3]);
                else         rs1 += (s[0]+s[1]) + (s[2]+s[3]);
                unsigned lo = __builtin_amdgcn_perm(__float_as_uint(s[1]), __float_as_uint(s[0]), 0x07060302u);
                unsigned hi = __builtin_amdgcn_perm(__float_as_uint(s[3]), __float_as_uint(s[2]), 0x07060302u);
                uint2 pk; pk.x = lo; pk.y = hi;
                *(uint2*)&lPw[(nq*16 + fr)*72 + mk*16 + quad4] = pk;
            }
        }

        short8 vf[4][2];
        #pragma unroll
        for (int nt=0;nt<4;nt++){
            int row = nt*16 + fr;
            vf[nt][0] = *(const short8*)&lV[row*64 + ((quad     ^ sw)<<3)];
            vf[nt][1] = *(const short8*)&lV[row*64 + (((4+quad) ^ sw)<<3)];
        }
        short8 pf[2][2];
        #pragma unroll
        for (int mt=0;mt<2;mt++){
            pf[mt][0] = *(const short8*)&lPw[(mt*16+fr)*72 + quad*8];
            pf[mt][1] = *(const short8*)&lPw[(mt*16+fr)*72 + 32 + quad*8];
        }
        __builtin_amdgcn_s_setprio(1);
        #pragma unroll
        for (int mt=0;mt<2;mt++)
            #pragma unroll
            for (int nt=0;nt<4;nt++){
                O[mt][nt] = MFMA16(pf[mt][0], vf[nt][0], O[mt][nt]);
                O[mt][nt] = MFMA16(pf[mt][1], vf[nt][1], O[mt][nt]);
            }
        __builtin_amdgcn_s_setprio(0);
    }

    rs0 += __shfl_xor(rs0, 16); rs0 += __shfl_xor(rs0, 32);
    rs1 += __shfl_xor(rs1, 16); rs1 += __shfl_xor(rs1, 32);
    if (lane < 16){
        linv[w][fr]      = 1.0f / rs0;
        linv[w][16 + fr] = 1.0f / rs1;
    }
    int tokbase = b*S_ + qt*128 + w*32;
    #pragma unroll
    for (int mt=0;mt<2;mt++){
        float4 iv = *(const float4*)&linv[w][mt*16 + quad4];
        #pragma unroll
        for (int nt=0;nt<4;nt++)
            #pragma unroll
            for (int r=0;r<4;r++){
                int tok = tokbase + mt*16 + quad4 + r;
                ctx[(size_t)tok*H_ + h*HD_ + nt*16 + fr] = f2bf(O[mt][nt][r] * (&iv.x)[r]);
            }
    }
}

// ---------------- LayerNorm (residual pre-added by gemm_o) ----------------
__global__ __launch_bounds__(192, 4) void resid_ln(
    const float* __restrict__ x,
    const float* __restrict__ g, const float* __restrict__ be,
    float* __restrict__ out)
{
    int row = blockIdx.x;
    int tid = threadIdx.x;            // 0..191
    float4 v = ((const float4*)(x + (size_t)row*H_))[tid];
    float s  = (v.x + v.y) + (v.z + v.w);
    float s2 = (v.x*v.x + v.y*v.y) + (v.z*v.z + v.w*v.w);
    #pragma unroll
    for (int off=1; off<64; off<<=1){
        s  += __shfl_xor(s,  off);
        s2 += __shfl_xor(s2, off);
    }
    __shared__ float rs[3], rs2[3];
    if ((tid & 63) == 0){ rs[tid>>6] = s; rs2[tid>>6] = s2; }
    __syncthreads();
    s  = rs[0]+rs[1]+rs[2];
    s2 = rs2[0]+rs2[1]+rs2[2];
    float mu  = s * (1.f/H_);
    float var = s2*(1.f/H_) - mu*mu;
    float rinv = rsqrtf(var + 1e-5f);
    float4 gg = ((const float4*)g)[tid];
    float4 bb = ((const float4*)be)[tid];
    float4 o;
    o.x = (v.x-mu)*rinv*gg.x + bb.x;
    o.y = (v.y-mu)*rinv*gg.y + bb.y;
    o.z = (v.z-mu)*rinv*gg.z + bb.z;
    o.w = (v.w-mu)*rinv*gg.w + bb.w;
    ((float4*)(out + (size_t)row*H_))[tid] = o;
}

extern "C" void kernel_launch(void* const* d_in, const int* in_sizes, int n_in,
                              void* d_out, int out_size, void* d_ws, size_t ws_size,
                              hipStream_t stream)
{
    (void)in_sizes; (void)n_in; (void)out_size; (void)ws_size;
    const float* hs   = (const float*)d_in[0];
    const float* ce   = (const float*)d_in[1];
    const float* mask = (const float*)d_in[2];
    const float* Wq   = (const float*)d_in[3];
    const float* bq   = (const float*)d_in[4];
    const float* Wk   = (const float*)d_in[5];
    const float* bk   = (const float*)d_in[6];
    const float* Wv   = (const float*)d_in[7];
    const float* bv   = (const float*)d_in[8];
    const float* Wo   = (const float*)d_in[9];
    const float* bo   = (const float*)d_in[10];
    const float* lg   = (const float*)d_in[11];
    const float* lb   = (const float*)d_in[12];
    float* out = (float*)d_out;

    char* ws = (char*)d_ws;
    const size_t SZ_ACT = (size_t)M_*H_*2;
    const size_t SZ_W   = (size_t)H_*H_*2;
    ushort* hsb  = (ushort*)(ws);
    ushort* ceb  = (ushort*)(ws + SZ_ACT);
    ushort* wqb  = (ushort*)(ws + 2*SZ_ACT);
    ushort* wkb  = (ushort*)(ws + 2*SZ_ACT + 1*SZ_W);
    ushort* wvb  = (ushort*)(ws + 2*SZ_ACT + 2*SZ_W);
    ushort* wob  = (ushort*)(ws + 2*SZ_ACT + 3*SZ_W);
    ushort* Qb   = (ushort*)(ws + 2*SZ_ACT + 4*SZ_W);
    ushort* Kb   = (ushort*)(ws + 3*SZ_ACT + 4*SZ_W);
    ushort* Vtb  = (ushort*)(ws + 4*SZ_ACT + 4*SZ_W);
    ushort* ctxb = (ushort*)(ws + 5*SZ_ACT + 4*SZ_W);
    float*  proj = (float*)(ws);  // aliases hsb+ceb (dead after QKV GEMMs)

    int ncvt = 2*(M_*H_/8) + 4*(H_*H_/8);
    cvt_all<<<dim3((ncvt+255)/256), dim3(256), 0, stream>>>(
        hs, ce, Wq, Wk, Wv, Wo, hsb, ceb, wqb, wkb, wvb, wob);

    gemm_qkv<<<dim3(M_/128, H_/96, 2), dim3(256), 0, stream>>>(
        hsb, ceb, wqb, wkb, wvb, bq, bk, bv, Qb, Kb, Vtb);

    attn<<<dim3(B_*NH_*8), dim3(256), 0, stream>>>(Qb, Kb, Vtb, mask, ctxb);

    gemm_o<<<dim3(M_/128, H_/96), dim3(256), 0, stream>>>(ctxb, wob, bo, hs, proj);

    resid_ln<<<dim3(M_), dim3(192), 0, stream>>>(proj, lg, lb, out);
}

// Round 12
// 216.176 us; speedup vs baseline: 1.6635x; 1.0263x over previous
//
#include <hip/hip_runtime.h>
#include <stdint.h>

#define B_ 8
#define S_ 1024
#define H_ 768
#define NH_ 12
#define HD_ 64
#define M_ (B_*S_)   // 8192 tokens

typedef __attribute__((ext_vector_type(8))) short short8;
typedef __attribute__((ext_vector_type(8))) ushort ushort8;
typedef __attribute__((ext_vector_type(4))) float floatx4;

#define MFMA16(a,b,c) __builtin_amdgcn_mfma_f32_16x16x32_bf16((a),(b),(c),0,0,0)

__device__ __forceinline__ ushort f2bf(float x){
    union { float f; unsigned u; } v; v.f = x;
    unsigned r = (v.u + 0x7fffu + ((v.u >> 16) & 1u)) >> 16;
    return (ushort)r;
}

__device__ __forceinline__ void async16(const ushort* g, ushort* l){
    __builtin_amdgcn_global_load_lds(
        (const __attribute__((address_space(1))) unsigned int*)g,
        (__attribute__((address_space(3))) unsigned int*)l, 16, 0, 0);
}

// ---------------- fused f32 -> bf16 cast for all 6 tensors ----------------
__global__ __launch_bounds__(256, 8) void cvt_all(
    const float* __restrict__ hs, const float* __restrict__ ce,
    const float* __restrict__ wq, const float* __restrict__ wk,
    const float* __restrict__ wv, const float* __restrict__ wo,
    ushort* __restrict__ hsb, ushort* __restrict__ ceb,
    ushort* __restrict__ wqb, ushort* __restrict__ wkb,
    ushort* __restrict__ wvb, ushort* __restrict__ wob)
{
    const int NA = M_*H_/8;
    const int NW = H_*H_/8;
    int i = blockIdx.x*256 + threadIdx.x;
    if (i >= 2*NA + 4*NW) return;
    const float* s; ushort* d; int off;
    if (i < NA)            { s = hs; d = hsb; off = i; }
    else if (i < 2*NA)     { s = ce; d = ceb; off = i - NA; }
    else {
        int j = i - 2*NA;
        int wsel = j / NW;
        off = j - wsel*NW;
        s = (wsel==0) ? wq : (wsel==1) ? wk : (wsel==2) ? wv : wo;
        d = (wsel==0) ? wqb : (wsel==1) ? wkb : (wsel==2) ? wvb : wob;
    }
    float4 f0 = ((const float4*)s)[2*off];
    float4 f1 = ((const float4*)s)[2*off + 1];
    ushort8 u;
    u[0] = f2bf(f0.x); u[1] = f2bf(f0.y); u[2] = f2bf(f0.z); u[3] = f2bf(f0.w);
    u[4] = f2bf(f1.x); u[5] = f2bf(f1.y); u[6] = f2bf(f1.z); u[7] = f2bf(f1.w);
    ((ushort8*)d)[off] = u;
}

// ---------------- shared GEMM body: C[M,N] = A[M,K] @ B[N,K]^T + bias ------
// BK=64, XOR-swizzled 128B-pitch LDS rows. smem DECLARED BY CALLER (round-8
// lesson). MODE 0: bf16 out; MODE 2: f32 out + residual.
template<int BN, int MODE>
__device__ __forceinline__ void gemm_body(
    ushort* __restrict__ smem,
    const ushort* __restrict__ A, const ushort* __restrict__ Bw,
    const float* __restrict__ bias, ushort* __restrict__ obf,
    float* __restrict__ of32, const float* __restrict__ resid,
    int bx, int by)
{
    constexpr int NT = BN/32;
    ushort* lA = smem;                      // [0, 8192)
    ushort* lB = smem + 8192;               // [8192, 8192+BN*64)
    const int K = H_;
    int tid  = threadIdx.x;
    int lane = tid & 63, wave = tid >> 6;
    int m0 = bx * 128, n0 = by * BN;
    int wm = (wave >> 1) * 64, wn = (wave & 1) * (BN/2);
    int fr = lane & 15, quad = lane >> 4, quad4 = quad*4;

    floatx4 acc[4][NT];
    #pragma unroll
    for (int mt=0;mt<4;mt++)
        #pragma unroll
        for (int nt=0;nt<NT;nt++)
            acc[mt][nt] = (floatx4){0.f,0.f,0.f,0.f};

    int row0 = tid >> 3;
    int csw  = ((tid & 7) ^ (row0 & 7)) * 8;
    const ushort* Ap[4]; const ushort* Bp[NT];
    ushort* ldA_[4]; ushort* ldB_[NT];
    #pragma unroll
    for (int j=0;j<4;j++){
        int row = row0 + 32*j;
        Ap[j] = A + (size_t)(m0 + row) * K + csw;
        ldA_[j] = lA + (tid + 256*j)*8;
    }
    #pragma unroll
    for (int j=0;j<NT;j++){
        int row = row0 + 32*j;
        Bp[j] = Bw + (size_t)(n0 + row) * K + csw;
        ldB_[j] = lB + (tid + 256*j)*8;
    }

    for (int k0 = 0; k0 < K; k0 += 64){
        #pragma unroll
        for (int j=0;j<4;j++) async16(Ap[j] + k0, ldA_[j]);
        #pragma unroll
        for (int j=0;j<NT;j++) async16(Bp[j] + k0, ldB_[j]);
        __syncthreads();
        #pragma unroll
        for (int kk=0; kk<2; kk++){
            short8 af[4], bfr[NT];
            #pragma unroll
            for (int t=0;t<4;t++){
                int ra = wm + t*16 + fr;
                af[t]  = *(const short8*)&lA[ra*64 + (((kk*4+quad) ^ (ra&7))<<3)];
            }
            #pragma unroll
            for (int t=0;t<NT;t++){
                int rb = wn + t*16 + fr;
                bfr[t] = *(const short8*)&lB[rb*64 + (((kk*4+quad) ^ (rb&7))<<3)];
            }
            #pragma unroll
            for (int mt=0;mt<4;mt++)
                #pragma unroll
                for (int nt=0;nt<NT;nt++)
                    acc[mt][nt] = MFMA16(af[mt], bfr[nt], acc[mt][nt]);
        }
        __syncthreads();
    }

    float bv_[NT];
    #pragma unroll
    for (int nt=0;nt<NT;nt++) bv_[nt] = bias[n0 + wn + nt*16 + fr];

    if constexpr (MODE == 0){
        #pragma unroll
        for (int mt=0;mt<4;mt++){
            int rb = m0 + wm + mt*16 + quad4;
            #pragma unroll
            for (int nt=0;nt<NT;nt++){
                int col = n0 + wn + nt*16 + fr;
                #pragma unroll
                for (int r=0;r<4;r++)
                    obf[(size_t)(rb + r)*H_ + col] = f2bf(acc[mt][nt][r] + bv_[nt]);
            }
        }
    } else {
        #pragma unroll
        for (int mt=0;mt<4;mt++){
            int rb = m0 + wm + mt*16 + quad4;
            #pragma unroll
            for (int nt=0;nt<NT;nt++){
                int col = n0 + wn + nt*16 + fr;
                #pragma unroll
                for (int r=0;r<4;r++){
                    size_t idx = (size_t)(rb + r)*H_ + col;
                    of32[idx] = acc[mt][nt][r] + bv_[nt] + resid[idx];
                }
            }
        }
    }
}

// -------- merged K+V body: both 96-col panels share ONE staged A tile -----
// 48 MFMA per barrier pair; proven round-11 (VGPR 84, no spill).
__device__ __forceinline__ void gemm_kv_body(
    ushort* __restrict__ smem,
    const ushort* __restrict__ A,
    const ushort* __restrict__ Bk, const ushort* __restrict__ Bv,
    const float* __restrict__ biask, const float* __restrict__ biasv,
    ushort* __restrict__ Kb, ushort* __restrict__ Vtb,
    int bx, int by)
{
    ushort* lA  = smem;             // 8192 ushorts
    ushort* lBK = smem + 8192;      // 6144
    ushort* lBV = smem + 14336;     // 6144
    const int K = H_;
    int tid  = threadIdx.x;
    int lane = tid & 63, wave = tid >> 6;
    int m0 = bx * 128, n0 = by * 96;
    int wm = (wave >> 1) * 64, wn = (wave & 1) * 48;
    int fr = lane & 15, quad = lane >> 4, quad4 = quad*4;

    floatx4 aK[4][3], aV[4][3];
    #pragma unroll
    for (int mt=0;mt<4;mt++)
        #pragma unroll
        for (int nt=0;nt<3;nt++){
            aK[mt][nt] = (floatx4){0.f,0.f,0.f,0.f};
            aV[mt][nt] = (floatx4){0.f,0.f,0.f,0.f};
        }

    int row0 = tid >> 3;
    int csw  = ((tid & 7) ^ (row0 & 7)) * 8;
    const ushort* Ap[4]; const ushort* Kp[3]; const ushort* Vp[3];
    ushort* ldA_[4]; ushort* ldK_[3]; ushort* ldV_[3];
    #pragma unroll
    for (int j=0;j<4;j++){
        int row = row0 + 32*j;
        Ap[j] = A + (size_t)(m0 + row) * K + csw;
        ldA_[j] = lA + (tid + 256*j)*8;
    }
    #pragma unroll
    for (int j=0;j<3;j++){
        int row = row0 + 32*j;
        Kp[j] = Bk + (size_t)(n0 + row) * K + csw;
        Vp[j] = Bv + (size_t)(n0 + row) * K + csw;
        ldK_[j] = lBK + (tid + 256*j)*8;
        ldV_[j] = lBV + (tid + 256*j)*8;
    }

    for (int k0 = 0; k0 < K; k0 += 64){
        #pragma unroll
        for (int j=0;j<4;j++) async16(Ap[j] + k0, ldA_[j]);
        #pragma unroll
        for (int j=0;j<3;j++) async16(Kp[j] + k0, ldK_[j]);
        #pragma unroll
        for (int j=0;j<3;j++) async16(Vp[j] + k0, ldV_[j]);
        __syncthreads();
        #pragma unroll
        for (int kk=0; kk<2; kk++){
            short8 af[4], bk_[3], bv2_[3];
            #pragma unroll
            for (int t=0;t<4;t++){
                int ra = wm + t*16 + fr;
                af[t] = *(const short8*)&lA[ra*64 + (((kk*4+quad) ^ (ra&7))<<3)];
            }
            #pragma unroll
            for (int t=0;t<3;t++){
                int rb = wn + t*16 + fr;
                int off = (((kk*4+quad) ^ (rb&7))<<3);
                bk_[t]  = *(const short8*)&lBK[rb*64 + off];
                bv2_[t] = *(const short8*)&lBV[rb*64 + off];
            }
            #pragma unroll
            for (int mt=0;mt<4;mt++)
                #pragma unroll
                for (int nt=0;nt<3;nt++){
                    aK[mt][nt] = MFMA16(af[mt], bk_[nt],  aK[mt][nt]);
                    aV[mt][nt] = MFMA16(af[mt], bv2_[nt], aV[mt][nt]);
                }
        }
        __syncthreads();
    }

    float bk4[3], bv4[3];
    #pragma unroll
    for (int nt=0;nt<3;nt++){
        bk4[nt] = biask[n0 + wn + nt*16 + fr];
        bv4[nt] = biasv[n0 + wn + nt*16 + fr];
    }

    // K epilogue
    #pragma unroll
    for (int mt=0;mt<4;mt++){
        int rb = m0 + wm + mt*16 + quad4;
        #pragma unroll
        for (int nt=0;nt<3;nt++){
            int col = n0 + wn + nt*16 + fr;
            #pragma unroll
            for (int r=0;r<4;r++)
                Kb[(size_t)(rb + r)*H_ + col] = f2bf(aK[mt][nt][r] + bk4[nt]);
        }
    }

    // V epilogue ([96 d][pitch 136 q] smem assembly, coalesced Vt stores)
    int bb = m0 >> 10, q0 = m0 & 1023;
    #pragma unroll
    for (int mt=0;mt<4;mt++){
        int ql = wm + mt*16 + quad4;
        #pragma unroll
        for (int nt=0;nt<3;nt++){
            int dl = wn + nt*16 + fr;          // 0..95
            ushort4 u;
            u.x = f2bf(aV[mt][nt][0] + bv4[nt]);
            u.y = f2bf(aV[mt][nt][1] + bv4[nt]);
            u.z = f2bf(aV[mt][nt][2] + bv4[nt]);
            u.w = f2bf(aV[mt][nt][3] + bv4[nt]);
            *(ushort4*)&smem[dl*136 + ql] = u;
        }
    }
    __syncthreads();
    #pragma unroll
    for (int jj=0;jj<6;jj++){
        int mI = tid + 256*jj;                 // 0..1535
        int d  = mI >> 4;                      // 0..95
        int qc = (mI & 15) * 8;
        short8 v = *(const short8*)&smem[d*136 + qc];
        int gcol = by*96 + d;
        int h = gcol >> 6, dd = gcol & 63;
        *(short8*)&Vtb[((size_t)((bb*NH_ + h)*HD_ + dd))*S_ + q0 + qc] = v;
    }
}

// QKV projection, single co-resident round: grid (64, 12) = 768 blocks =
// exactly 3 blocks/CU x 256 CU. by<4: Q at BN=192 (256 blocks, 48 MFMA per
// barrier pair like the KV body); by>=4: merged K+V (512 blocks). Uniform
// LDS 40960 B. Round-11 had 1024 blocks -> 1.33 ragged rounds; this is 1.0.
__global__ __launch_bounds__(256, 3) void gemm_qkv(
    const ushort* __restrict__ hsb, const ushort* __restrict__ ceb,
    const ushort* __restrict__ wqb, const ushort* __restrict__ wkb,
    const ushort* __restrict__ wvb,
    const float* __restrict__ bq, const float* __restrict__ bk,
    const float* __restrict__ bv,
    ushort* __restrict__ Qb, ushort* __restrict__ Kb, ushort* __restrict__ Vtb)
{
    __shared__ ushort smem[20480];   // 40960 B single allocation
    int by = blockIdx.y;
    if (by < 4)
        gemm_body<192,0>(smem, hsb, wqb, bq, Qb, nullptr, nullptr,
                         blockIdx.x, by);
    else
        gemm_kv_body(smem, ceb, wkb, wvb, bk, bv, Kb, Vtb,
                     blockIdx.x, by - 4);
}

// O-projection (f32 out, + residual hs fused): grid (64, 8), BN=96
__global__ __launch_bounds__(256, 3) void gemm_o(
    const ushort* __restrict__ ctxb, const ushort* __restrict__ wob,
    const float* __restrict__ bo, const float* __restrict__ hs,
    float* __restrict__ proj)
{
    __shared__ ushort smem[8192 + 96*64];   // 28672 B
    gemm_body<96,2>(smem, ctxb, wob, bo, nullptr, proj, hs,
                    blockIdx.x, blockIdx.y);
}

// ---------------- flash attention (S^T formulation) ----------------
// FROZEN = round-5 v6 verbatim (44.0us, four-times-measured).
__global__ __launch_bounds__(256, 3) void attn(
    const ushort* __restrict__ Q, const ushort* __restrict__ Kc,
    const ushort* __restrict__ Vt, const float* __restrict__ mask,
    ushort* __restrict__ ctx)
{
    __shared__ ushort lK[64*64];
    __shared__ ushort lV[64*64];
    __shared__ ushort lP[4][32*72];
    __shared__ float  lmask[S_];
    __shared__ float  linv[4][32];

    const float SC = 0.125f * 1.44269504f;

    int bid = blockIdx.x;
    int qt = bid & 7;
    int h  = (bid >> 3) % NH_;
    int b  = bid / (8*NH_);

    int tid  = threadIdx.x;
    int lane = tid & 63, w = tid >> 6;
    int fr = lane & 15, quad = lane >> 4;
    int quad4 = quad*4, sw = fr & 7;

    for (int i = tid; i < S_; i += 256)
        lmask[i] = (1.0f - mask[b*S_ + i]) * -14426.95f;

    short8 qf[2][2];
    #pragma unroll
    for (int nq=0;nq<2;nq++){
        const ushort* Qp = Q + (size_t)(b*S_ + qt*128 + w*32 + nq*16 + fr)*H_ + h*HD_ + quad*8;
        qf[nq][0] = *(const short8*)(Qp);
        qf[nq][1] = *(const short8*)(Qp + 32);
    }

    floatx4 O[2][4];
    #pragma unroll
    for (int mt=0;mt<2;mt++)
        #pragma unroll
        for (int nt=0;nt<4;nt++)
            O[mt][nt] = (floatx4){0.f,0.f,0.f,0.f};
    float rs0 = 0.f, rs1 = 0.f;

    int n0 = tid,       r0 = n0 >> 3, c0 = (n0 & 7) ^ (r0 & 7);
    int n1 = 256 + tid, r1 = n1 >> 3, c1 = (n1 & 7) ^ (r1 & 7);
    const ushort* pK0 = Kc + (size_t)(b*S_ + r0)*H_ + h*HD_ + c0*8;
    const ushort* pK1 = Kc + (size_t)(b*S_ + r1)*H_ + h*HD_ + c1*8;
    const ushort* pV0 = Vt + ((size_t)(b*NH_ + h)*HD_ + r0)*S_ + c0*8;
    const ushort* pV1 = Vt + ((size_t)(b*NH_ + h)*HD_ + r1)*S_ + c1*8;
    ushort* dK0 = &lK[n0*8]; ushort* dK1 = &lK[n1*8];
    ushort* dV0 = &lV[n0*8]; ushort* dV1 = &lV[n1*8];

    ushort* lPw = &lP[w][0];

    for (int kt = 0; kt < 16; kt++){
        __syncthreads();
        async16(pK0, dK0); async16(pK1, dK1);
        async16(pV0, dV0); async16(pV1, dV1);
        pK0 += (size_t)64*H_; pK1 += (size_t)64*H_;
        pV0 += 64; pV1 += 64;
        __syncthreads();

        float4 mk4[4];
        #pragma unroll
        for (int mk=0;mk<4;mk++)
            mk4[mk] = *(const float4*)&lmask[kt*64 + mk*16 + quad4];

        short8 kf[4][2];
        #pragma unroll
        for (int mk=0;mk<4;mk++){
            int row = mk*16 + fr;
            kf[mk][0] = *(const short8*)&lK[row*64 + ((quad     ^ sw)<<3)];
            kf[mk][1] = *(const short8*)&lK[row*64 + (((4+quad) ^ sw)<<3)];
        }
        __builtin_amdgcn_s_setprio(1);
        floatx4 st[2][4];
        #pragma unroll
        for (int nq=0;nq<2;nq++)
            #pragma unroll
            for (int mk=0;mk<4;mk++){
                floatx4 a = (floatx4){0.f,0.f,0.f,0.f};
                a = MFMA16(kf[mk][0], qf[nq][0], a);
                a = MFMA16(kf[mk][1], qf[nq][1], a);
                st[nq][mk] = a;
            }
        __builtin_amdgcn_s_setprio(0);

        #pragma unroll
        for (int nq=0;nq<2;nq++){
            #pragma unroll
            for (int mk=0;mk<4;mk++){
                floatx4 s = st[nq][mk];
                #pragma unroll
                for (int r=0;r<4;r++)
                    s[r] = __builtin_amdgcn_exp2f(s[r]*SC + mk4[mk][r]);
                if (nq == 0) rs0 += (s[0]+s[1]) + (s[2]+s[3]);
                else         rs1 += (s[0]+s[1]) + (s[2]+s[3]);
                unsigned lo = __builtin_amdgcn_perm(__float_as_uint(s[1]), __float_as_uint(s[0]), 0x07060302u);
                unsigned hi = __builtin_amdgcn_perm(__float_as_uint(s[3]), __float_as_uint(s[2]), 0x07060302u);
                uint2 pk; pk.x = lo; pk.y = hi;
                *(uint2*)&lPw[(nq*16 + fr)*72 + mk*16 + quad4] = pk;
            }
        }

        short8 vf[4][2];
        #pragma unroll
        for (int nt=0;nt<4;nt++){
            int row = nt*16 + fr;
            vf[nt][0] = *(const short8*)&lV[row*64 + ((quad     ^ sw)<<3)];
            vf[nt][1] = *(const short8*)&lV[row*64 + (((4+quad) ^ sw)<<3)];
        }
        short8 pf[2][2];
        #pragma unroll
        for (int mt=0;mt<2;mt++){
            pf[mt][0] = *(const short8*)&lPw[(mt*16+fr)*72 + quad*8];
            pf[mt][1] = *(const short8*)&lPw[(mt*16+fr)*72 + 32 + quad*8];
        }
        __builtin_amdgcn_s_setprio(1);
        #pragma unroll
        for (int mt=0;mt<2;mt++)
            #pragma unroll
            for (int nt=0;nt<4;nt++){
                O[mt][nt] = MFMA16(pf[mt][0], vf[nt][0], O[mt][nt]);
                O[mt][nt] = MFMA16(pf[mt][1], vf[nt][1], O[mt][nt]);
            }
        __builtin_amdgcn_s_setprio(0);
    }

    rs0 += __shfl_xor(rs0, 16); rs0 += __shfl_xor(rs0, 32);
    rs1 += __shfl_xor(rs1, 16); rs1 += __shfl_xor(rs1, 32);
    if (lane < 16){
        linv[w][fr]      = 1.0f / rs0;
        linv[w][16 + fr] = 1.0f / rs1;
    }
    int tokbase = b*S_ + qt*128 + w*32;
    #pragma unroll
    for (int mt=0;mt<2;mt++){
        float4 iv = *(const float4*)&linv[w][mt*16 + quad4];
        #pragma unroll
        for (int nt=0;nt<4;nt++)
            #pragma unroll
            for (int r=0;r<4;r++){
                int tok = tokbase + mt*16 + quad4 + r;
                ctx[(size_t)tok*H_ + h*HD_ + nt*16 + fr] = f2bf(O[mt][nt][r] * (&iv.x)[r]);
            }
    }
}

// ---------------- LayerNorm (residual pre-added by gemm_o) ----------------
__global__ __launch_bounds__(192, 4) void resid_ln(
    const float* __restrict__ x,
    const float* __restrict__ g, const float* __restrict__ be,
    float* __restrict__ out)
{
    int row = blockIdx.x;
    int tid = threadIdx.x;            // 0..191
    float4 v = ((const float4*)(x + (size_t)row*H_))[tid];
    float s  = (v.x + v.y) + (v.z + v.w);
    float s2 = (v.x*v.x + v.y*v.y) + (v.z*v.z + v.w*v.w);
    #pragma unroll
    for (int off=1; off<64; off<<=1){
        s  += __shfl_xor(s,  off);
        s2 += __shfl_xor(s2, off);
    }
    __shared__ float rs[3], rs2[3];
    if ((tid & 63) == 0){ rs[tid>>6] = s; rs2[tid>>6] = s2; }
    __syncthreads();
    s  = rs[0]+rs[1]+rs[2];
    s2 = rs2[0]+rs2[1]+rs2[2];
    float mu  = s * (1.f/H_);
    float var = s2*(1.f/H_) - mu*mu;
    float rinv = rsqrtf(var + 1e-5f);
    float4 gg = ((const float4*)g)[tid];
    float4 bb = ((const float4*)be)[tid];
    float4 o;
    o.x = (v.x-mu)*rinv*gg.x + bb.x;
    o.y = (v.y-mu)*rinv*gg.y + bb.y;
    o.z = (v.z-mu)*rinv*gg.z + bb.z;
    o.w = (v.w-mu)*rinv*gg.w + bb.w;
    ((float4*)(out + (size_t)row*H_))[tid] = o;
}

extern "C" void kernel_launch(void* const* d_in, const int* in_sizes, int n_in,
                              void* d_out, int out_size, void* d_ws, size_t ws_size,
                              hipStream_t stream)
{
    (void)in_sizes; (void)n_in; (void)out_size; (void)ws_size;
    const float* hs   = (const float*)d_in[0];
    const float* ce   = (const float*)d_in[1];
    const float* mask = (const float*)d_in[2];
    const float* Wq   = (const float*)d_in[3];
    const float* bq   = (const float*)d_in[4];
    const float* Wk   = (const float*)d_in[5];
    const float* bk   = (const float*)d_in[6];
    const float* Wv   = (const float*)d_in[7];
    const float* bv   = (const float*)d_in[8];
    const float* Wo   = (const float*)d_in[9];
    const float* bo   = (const float*)d_in[10];
    const float* lg   = (const float*)d_in[11];
    const float* lb   = (const float*)d_in[12];
    float* out = (float*)d_out;

    char* ws = (char*)d_ws;
    const size_t SZ_ACT = (size_t)M_*H_*2;
    const size_t SZ_W   = (size_t)H_*H_*2;
    ushort* hsb  = (ushort*)(ws);
    ushort* ceb  = (ushort*)(ws + SZ_ACT);
    ushort* wqb  = (ushort*)(ws + 2*SZ_ACT);
    ushort* wkb  = (ushort*)(ws + 2*SZ_ACT + 1*SZ_W);
    ushort* wvb  = (ushort*)(ws + 2*SZ_ACT + 2*SZ_W);
    ushort* wob  = (ushort*)(ws + 2*SZ_ACT + 3*SZ_W);
    ushort* Qb   = (ushort*)(ws + 2*SZ_ACT + 4*SZ_W);
    ushort* Kb   = (ushort*)(ws + 3*SZ_ACT + 4*SZ_W);
    ushort* Vtb  = (ushort*)(ws + 4*SZ_ACT + 4*SZ_W);
    ushort* ctxb = (ushort*)(ws + 5*SZ_ACT + 4*SZ_W);
    float*  proj = (float*)(ws);  // aliases hsb+ceb (dead after QKV GEMMs)

    int ncvt = 2*(M_*H_/8) + 4*(H_*H_/8);
    cvt_all<<<dim3((ncvt+255)/256), dim3(256), 0, stream>>>(
        hs, ce, Wq, Wk, Wv, Wo, hsb, ceb, wqb, wkb, wvb, wob);

    gemm_qkv<<<dim3(M_/128, 12), dim3(256), 0, stream>>>(
        hsb, ceb, wqb, wkb, wvb, bq, bk, bv, Qb, Kb, Vtb);

    attn<<<dim3(B_*NH_*8), dim3(256), 0, stream>>>(Qb, Kb, Vtb, mask, ctxb);

    gemm_o<<<dim3(M_/128, H_/96), dim3(256), 0, stream>>>(ctxb, wob, bo, hs, proj);

    resid_ln<<<dim3(M_), dim3(192), 0, stream>>>(proj, lg, lb, out);
}